// Round 4
// baseline (112.415 us; speedup 1.0000x reference)
//
#include <hip/hip_runtime.h>
#include <hip/hip_bf16.h>

#define MULC 128
#define IN_DIM 1152
#define ROWS_PER_WG 64
#define NTHREADS 256

typedef __attribute__((ext_vector_type(8))) short bf16x8;
typedef __attribute__((ext_vector_type(4))) float f32x4;

// LDS: ushort[16384] W1T (32 KB, bf16, swizzled) + float[12288] A-half-tile
// (48 KB, f32, swizzled 16B granules) = 80 KB exactly -> 2 blocks/CU.
#define W1T_USHORTS 16384

__device__ __forceinline__ unsigned short bfu(float f) {
    __hip_bfloat16 h = __float2bfloat16(f);      // HW cvt, RNE
    return __builtin_bit_cast(unsigned short, h);
}

__global__ __launch_bounds__(NTHREADS, 2)
void nltp_kernel(const float* __restrict__ x, const float* __restrict__ W1,
                 const float* __restrict__ W2, const float* __restrict__ tpw,
                 float* __restrict__ out)
{
    __shared__ __align__(16) unsigned short lds[16384 + 24576];
    unsigned short* ldsW = lds;
    float4* ldsA = (float4*)(lds + W1T_USHORTS);   // 3072 granules of 16 B

    const int t  = threadIdx.x;
    const int n0 = blockIdx.x * ROWS_PER_WG;
    const int l  = t & 63;
    const int w  = t >> 6;      // wave 0..3 owns rows [16w,16w+16)
    const int g  = l >> 4;      // k-group 0..3
    const int li = l & 15;
    const int ar  = 16 * w + li;
    const int arh = ar & 7;
    const int lih = li & 7;

    // ---- issue h0 x-loads: flat-dense, each inst = contiguous 1KB across wave ----
    float4 buf[12];
#pragma unroll
    for (int m = 0; m < 12; ++m) {
        int idx = 256 * m + t;          // 16B granule index 0..3071
        int rr  = idx / 48;             // row 0..63   (768 B per row per half)
        int G   = idx % 48;             // granule within row-half
        buf[m] = *(const float4*)(x + (size_t)(n0 + rr) * IN_DIM + MULC + 4 * G);
    }

    // ---- W1^T staging (overlaps x-load latency) ----
#pragma unroll 4
    for (int it = 0; it < 16; ++it) {
        int idx = it * 256 + t;         // float4 index 0..4095 over W1
        int u   = idx >> 5;
        int v4  = idx & 31;
        float4 f = ((const float4*)W1)[idx];
        int ug = u >> 3, ur = u & 7;
#pragma unroll
        for (int e = 0; e < 4; ++e) {
            int v = 4 * v4 + e;
            ldsW[v * 128 + (((ug) ^ (v & 7)) << 3) + ur] =
                bfu(e == 0 ? f.x : e == 1 ? f.y : e == 2 ? f.z : f.w);
        }
    }

    f32x4 acc[3][8];
#pragma unroll
    for (int c = 0; c < 3; ++c)
#pragma unroll
        for (int nt = 0; nt < 8; ++nt)
            acc[c][nt] = (f32x4){0.f, 0.f, 0.f, 0.f};

#pragma unroll
    for (int h = 0; h < 2; ++h) {
        // ---- ds_write this half's tile (swizzled granules) ----
#pragma unroll
        for (int m = 0; m < 12; ++m) {
            int idx = 256 * m + t;
            int rr  = idx / 48;
            int G   = idx % 48;
            ldsA[rr * 48 + (G ^ (rr & 7))] = buf[m];
        }
        // ---- issue next half's loads (in flight across h0 compute) ----
        if (h == 0) {
#pragma unroll
            for (int m = 0; m < 12; ++m) {
                int idx = 256 * m + t;
                int rr  = idx / 48;
                int G   = idx % 48;
                buf[m] = *(const float4*)(x + (size_t)(n0 + rr) * IN_DIM + MULC + 192 + 4 * G);
            }
        }
        __syncthreads();

        // ---- compute 2 K-steps from LDS ----
#pragma unroll
        for (int kcl = 0; kcl < 2; ++kcl) {
            float4 rv[6];
#pragma unroll
            for (int j = 0; j < 6; ++j)
                rv[j] = ldsA[ar * 48 + ((24 * kcl + 6 * g + j) ^ arh)];
            const float* f = (const float*)rv;
            bf16x8 F0, F1, F2;
#pragma unroll
            for (int s = 0; s < 8; ++s) {
                F0[s] = (short)bfu(f[3 * s + 0]);
                F1[s] = (short)bfu(f[3 * s + 1]);
                F2[s] = (short)bfu(f[3 * s + 2]);
            }
            const int ukk = 8 * h + 4 * kcl + g;   // u-granule 0..15
#pragma unroll
            for (int nt = 0; nt < 8; ++nt) {
                bf16x8 bfr = *(const bf16x8*)&ldsW[(nt * 16 + li) * 128 + ((ukk ^ lih) << 3)];
                acc[0][nt] = __builtin_amdgcn_mfma_f32_16x16x32_bf16(F0, bfr, acc[0][nt], 0, 0, 0);
                acc[1][nt] = __builtin_amdgcn_mfma_f32_16x16x32_bf16(F1, bfr, acc[1][nt], 0, 0, 0);
                acc[2][nt] = __builtin_amdgcn_mfma_f32_16x16x32_bf16(F2, bfr, acc[2][nt], 0, 0, 0);
            }
        }
        if (h == 0) __syncthreads();   // tile reads done before overwrite
    }

    // ---- epilogue: silu + W2 contraction + 16-lane reduce + TP readout ----
    const float inv = 0.08838834764831845f;  // 1/sqrt(128)
    float w2a[8], w2b[8];
#pragma unroll
    for (int nt = 0; nt < 8; ++nt) {
        float2 p = *(const float2*)(W2 + 2 * (nt * 16 + li));
        w2a[nt] = p.x; w2b[nt] = p.y;
    }
    float pa[3][4], pb[3][4];
#pragma unroll
    for (int c = 0; c < 3; ++c)
#pragma unroll
        for (int rg = 0; rg < 4; ++rg) { pa[c][rg] = 0.f; pb[c][rg] = 0.f; }

#pragma unroll
    for (int c = 0; c < 3; ++c)
#pragma unroll
        for (int nt = 0; nt < 8; ++nt)
#pragma unroll
            for (int rg = 0; rg < 4; ++rg) {
                float y = acc[c][nt][rg] * inv;
                float e = __expf(-y);
                float s = y * __builtin_amdgcn_rcpf(1.f + e);   // silu
                pa[c][rg] += s * w2a[nt];
                pb[c][rg] += s * w2b[nt];
            }

#pragma unroll
    for (int c = 0; c < 3; ++c)
#pragma unroll
        for (int rg = 0; rg < 4; ++rg) {
            float va = pa[c][rg], vb = pb[c][rg];
            va += __shfl_xor(va, 1, 16); vb += __shfl_xor(vb, 1, 16);
            va += __shfl_xor(va, 2, 16); vb += __shfl_xor(vb, 2, 16);
            va += __shfl_xor(va, 4, 16); vb += __shfl_xor(vb, 4, 16);
            va += __shfl_xor(va, 8, 16); vb += __shfl_xor(vb, 8, 16);
            pa[c][rg] = va * inv;
            pb[c][rg] = vb * inv;
        }

    const float tw0 = tpw[0], tw1 = tpw[1], tw2 = tpw[2];
    const float k0 = tw0 * 0.5773502691896258f;   // 1/sqrt(3)
    const float k1 = tw1 * 0.7071067811865476f;   // sqrt(3)/sqrt(6)
    const float s2 = 0.7071067811865476f;
    const float s6 = 0.4082482904638631f;         // 1/sqrt(6)

#pragma unroll
    for (int rg = 0; rg < 4; ++rg) {
        float a_0 = pa[0][rg], a_1 = pa[1][rg], a_2 = pa[2][rg];
        float b_0 = pb[0][rg], b_1 = pb[1][rg], b_2 = pb[2][rg];
        float o0 = k0 * (a_0 * b_0 + a_1 * b_1 + a_2 * b_2);
        float o1 = k1 * (a_1 * b_2 - a_2 * b_1);
        float o2 = k1 * (a_2 * b_0 - a_0 * b_2);
        float o3 = k1 * (a_0 * b_1 - a_1 * b_0);
        float o4 = tw2 * (s2 * (a_2 * b_0 + a_0 * b_2));
        float o5 = tw2 * (s2 * (a_0 * b_1 + a_1 * b_0));
        float o6 = tw2 * (s6 * (2.f * a_1 * b_1 - a_2 * b_2 - a_0 * b_0));
        float o7 = tw2 * (s2 * (a_2 * b_1 + a_1 * b_2));
        float o8 = tw2 * (s2 * (a_2 * b_2 - a_0 * b_0));
        float o = li == 0 ? o0 : li == 1 ? o1 : li == 2 ? o2 : li == 3 ? o3 :
                  li == 4 ? o4 : li == 5 ? o5 : li == 6 ? o6 : li == 7 ? o7 : o8;
        if (li < 9) {
            int row = n0 + 16 * w + 4 * g + rg;
            out[row * 9 + li] = o;
        }
    }
}

extern "C" void kernel_launch(void* const* d_in, const int* in_sizes, int n_in,
                              void* d_out, int out_size, void* d_ws, size_t ws_size,
                              hipStream_t stream) {
    const float* x   = (const float*)d_in[0];
    const float* W1  = (const float*)d_in[1];
    const float* W2  = (const float*)d_in[2];
    const float* tpw = (const float*)d_in[3];
    float* out = (float*)d_out;
    const int n = in_sizes[0] / IN_DIM;           // 131072
    dim3 grid(n / ROWS_PER_WG);                   // 2048
    nltp_kernel<<<grid, NTHREADS, 0, stream>>>(x, W1, W2, tpw, out);
}

// Round 5
// 74.557 us; speedup vs baseline: 1.5078x; 1.5078x over previous
//
#include <hip/hip_runtime.h>
#include <hip/hip_bf16.h>

#define IN_DIM 1152
#define NTHREADS 256
#define ROWS_PER_WG 128
#define TILES 8               // 16-row tiles per block
#define AG_BUF 768            // 16-B granules per A buffer (3 planes x 256)
#define PART_BASE 24576       // byte offset of partials region
#define PART_FLTS 384         // floats per parity

typedef __attribute__((ext_vector_type(8))) short bf16x8;
typedef __attribute__((ext_vector_type(4))) float f32x4;

__device__ __forceinline__ short bfu(float f) {
    __hip_bfloat16 h = __float2bfloat16(f);     // HW cvt, RNE
    return __builtin_bit_cast(short, h);
}

__global__ __launch_bounds__(NTHREADS, 4)
void nltp_kernel(const float* __restrict__ x, const float* __restrict__ W1,
                 const float* __restrict__ W2, const float* __restrict__ tpw,
                 float* __restrict__ out)
{
    __shared__ __align__(16) unsigned char ldsraw[24576 + 2 * PART_FLTS * 4];
    float4* ldsA = (float4*)ldsraw;                    // granule-addressed A tiles
    float*  ldsP = (float*)(ldsraw + PART_BASE);       // partials [par][w][row][c][ab]

    const int t  = threadIdx.x;
    const int n0 = blockIdx.x * ROWS_PER_WG;
    const int l  = t & 63;
    const int w  = t >> 6;       // wave 0..3 owns v in [32w, 32w+32)
    const int g  = l >> 4;       // k-group / row-group
    const int li = l & 15;
    const int lih = li & 7;

    // staging assignment: thread (sr, so) loads row sr, u-octet so (24 floats)
    const int sr = t >> 4;       // local row 0..15
    const int so = t & 15;       // u-octet 0..15
    const float* xs = x + (size_t)(n0 + sr) * IN_DIM + 128 + 24 * so;

    // ---- issue tile-0 x loads (in flight during W1 gather) ----
    float4 sb0, sb1, sb2, sb3, sb4, sb5;
    {
        const float4* p = (const float4*)xs;
        sb0 = p[0]; sb1 = p[1]; sb2 = p[2]; sb3 = p[3]; sb4 = p[4]; sb5 = p[5];
    }

    // ---- W1 fragments into registers (once per block; L2-resident) ----
    bf16x8 w1f[2][4];
    float w2a[2], w2b[2];
#pragma unroll
    for (int n2 = 0; n2 < 2; ++n2) {
        const int v = 32 * w + 16 * n2 + li;
#pragma unroll
        for (int kc = 0; kc < 4; ++kc) {
            const int ub = 32 * kc + 8 * g;
            bf16x8 f;
#pragma unroll
            for (int j = 0; j < 8; ++j)
                f[j] = bfu(W1[(ub + j) * 128 + v]);
            w1f[n2][kc] = f;
        }
        float2 p2 = *(const float2*)(W2 + 2 * v);
        w2a[n2] = p2.x; w2b[n2] = p2.y;
    }
    const float tw0 = tpw[0], tw1 = tpw[1], tw2 = tpw[2];

    // ---- write tile 0 to LDS (bf16, c-deinterleaved, swizzled octets) ----
    {
        float fl[24];
        *(float4*)&fl[0] = sb0; *(float4*)&fl[4]  = sb1; *(float4*)&fl[8]  = sb2;
        *(float4*)&fl[12] = sb3; *(float4*)&fl[16] = sb4; *(float4*)&fl[20] = sb5;
        bf16x8 F0, F1, F2;
#pragma unroll
        for (int s = 0; s < 8; ++s) {
            F0[s] = bfu(fl[3 * s + 0]); F1[s] = bfu(fl[3 * s + 1]); F2[s] = bfu(fl[3 * s + 2]);
        }
        const int gr = sr * 16 + (so ^ (sr & 7));
        ldsA[gr] = __builtin_bit_cast(float4, F0);
        ldsA[gr + 256] = __builtin_bit_cast(float4, F1);
        ldsA[gr + 512] = __builtin_bit_cast(float4, F2);
    }
    __syncthreads();

    const float inv = 0.08838834764831845f;          // 1/sqrt(128)
    const float k0 = tw0 * 0.5773502691896258f;      // tw0/sqrt(3)
    const float k1 = tw1 * 0.7071067811865476f;      // tw1*sqrt(3)/sqrt(6)
    const float s2c = 0.7071067811865476f;
    const float s6c = 0.4082482904638631f;

    for (int tt = 0; tt < TILES; ++tt) {
        const int par = tt & 1;
        // ---- issue next tile's loads (overlap with MFMA below) ----
        if (tt < TILES - 1) {
            const float4* p = (const float4*)(xs + (size_t)(tt + 1) * 16 * IN_DIM);
            sb0 = p[0]; sb1 = p[1]; sb2 = p[2]; sb3 = p[3]; sb4 = p[4]; sb5 = p[5];
        }

        // ---- K loop: 4 kc, fragments from LDS, W1 from registers ----
        f32x4 acc[2][3];
#pragma unroll
        for (int n2 = 0; n2 < 2; ++n2)
#pragma unroll
            for (int c = 0; c < 3; ++c)
                acc[n2][c] = (f32x4){0.f, 0.f, 0.f, 0.f};
#pragma unroll
        for (int kc = 0; kc < 4; ++kc) {
            const int gb = par * AG_BUF + li * 16 + ((4 * kc + g) ^ lih);
            bf16x8 A0 = __builtin_bit_cast(bf16x8, ldsA[gb]);
            bf16x8 A1 = __builtin_bit_cast(bf16x8, ldsA[gb + 256]);
            bf16x8 A2 = __builtin_bit_cast(bf16x8, ldsA[gb + 512]);
#pragma unroll
            for (int n2 = 0; n2 < 2; ++n2) {
                acc[n2][0] = __builtin_amdgcn_mfma_f32_16x16x32_bf16(A0, w1f[n2][kc], acc[n2][0], 0, 0, 0);
                acc[n2][1] = __builtin_amdgcn_mfma_f32_16x16x32_bf16(A1, w1f[n2][kc], acc[n2][1], 0, 0, 0);
                acc[n2][2] = __builtin_amdgcn_mfma_f32_16x16x32_bf16(A2, w1f[n2][kc], acc[n2][2], 0, 0, 0);
            }
        }

        // ---- epilogue partials: silu + W2 + 16-lane reduce ----
        float pa[3][4], pb[3][4];
#pragma unroll
        for (int c = 0; c < 3; ++c)
#pragma unroll
            for (int rg = 0; rg < 4; ++rg) { pa[c][rg] = 0.f; pb[c][rg] = 0.f; }
#pragma unroll
        for (int n2 = 0; n2 < 2; ++n2)
#pragma unroll
            for (int c = 0; c < 3; ++c)
#pragma unroll
                for (int rg = 0; rg < 4; ++rg) {
                    float y = acc[n2][c][rg] * inv;
                    float s = y / (1.f + __expf(-y));
                    pa[c][rg] += s * w2a[n2];
                    pb[c][rg] += s * w2b[n2];
                }
#pragma unroll
        for (int c = 0; c < 3; ++c)
#pragma unroll
            for (int rg = 0; rg < 4; ++rg) {
                float va = pa[c][rg], vb = pb[c][rg];
                va += __shfl_xor(va, 1, 16); vb += __shfl_xor(vb, 1, 16);
                va += __shfl_xor(va, 2, 16); vb += __shfl_xor(vb, 2, 16);
                va += __shfl_xor(va, 4, 16); vb += __shfl_xor(vb, 4, 16);
                va += __shfl_xor(va, 8, 16); vb += __shfl_xor(vb, 8, 16);
                pa[c][rg] = va * inv; pb[c][rg] = vb * inv;
            }
        if (li == 0) {
#pragma unroll
            for (int rg = 0; rg < 4; ++rg) {
                const int base = par * PART_FLTS + w * 96 + (4 * g + rg) * 6;
#pragma unroll
                for (int c = 0; c < 3; ++c) {
                    ldsP[base + 2 * c + 0] = pa[c][rg];
                    ldsP[base + 2 * c + 1] = pb[c][rg];
                }
            }
        }
        __syncthreads();

        // ---- readout: wave w handles rows [4w,4w+4), lane li = component ----
        {
            const int rr = l >> 4;
            const int row = 4 * w + rr;
            float a0 = 0.f, a1 = 0.f, a2 = 0.f, b0 = 0.f, b1 = 0.f, b2 = 0.f;
#pragma unroll
            for (int sw = 0; sw < 4; ++sw) {
                const int base = par * PART_FLTS + sw * 96 + row * 6;
                a0 += ldsP[base + 0]; b0 += ldsP[base + 1];
                a1 += ldsP[base + 2]; b1 += ldsP[base + 3];
                a2 += ldsP[base + 4]; b2 += ldsP[base + 5];
            }
            float o0 = k0 * (a0 * b0 + a1 * b1 + a2 * b2);
            float o1 = k1 * (a1 * b2 - a2 * b1);
            float o2 = k1 * (a2 * b0 - a0 * b2);
            float o3 = k1 * (a0 * b1 - a1 * b0);
            float o4 = tw2 * (s2c * (a2 * b0 + a0 * b2));
            float o5 = tw2 * (s2c * (a0 * b1 + a1 * b0));
            float o6 = tw2 * (s6c * (2.f * a1 * b1 - a2 * b2 - a0 * b0));
            float o7 = tw2 * (s2c * (a2 * b1 + a1 * b2));
            float o8 = tw2 * (s2c * (a2 * b2 - a0 * b0));
            float o = li == 0 ? o0 : li == 1 ? o1 : li == 2 ? o2 : li == 3 ? o3 :
                      li == 4 ? o4 : li == 5 ? o5 : li == 6 ? o6 : li == 7 ? o7 : o8;
            if (li < 9)
                out[(size_t)(n0 + 16 * tt + row) * 9 + li] = o;
        }

        // ---- write next tile into other A buffer ----
        if (tt < TILES - 1) {
            float fl[24];
            *(float4*)&fl[0] = sb0; *(float4*)&fl[4]  = sb1; *(float4*)&fl[8]  = sb2;
            *(float4*)&fl[12] = sb3; *(float4*)&fl[16] = sb4; *(float4*)&fl[20] = sb5;
            bf16x8 F0, F1, F2;
#pragma unroll
            for (int s = 0; s < 8; ++s) {
                F0[s] = bfu(fl[3 * s + 0]); F1[s] = bfu(fl[3 * s + 1]); F2[s] = bfu(fl[3 * s + 2]);
            }
            const int gr = (par ^ 1) * AG_BUF + sr * 16 + (so ^ (sr & 7));
            ldsA[gr] = __builtin_bit_cast(float4, F0);
            ldsA[gr + 256] = __builtin_bit_cast(float4, F1);
            ldsA[gr + 512] = __builtin_bit_cast(float4, F2);
            __syncthreads();
        }
    }
}

extern "C" void kernel_launch(void* const* d_in, const int* in_sizes, int n_in,
                              void* d_out, int out_size, void* d_ws, size_t ws_size,
                              hipStream_t stream) {
    const float* x   = (const float*)d_in[0];
    const float* W1  = (const float*)d_in[1];
    const float* W2  = (const float*)d_in[2];
    const float* tpw = (const float*)d_in[3];
    float* out = (float*)d_out;
    const int n = in_sizes[0] / IN_DIM;            // 131072
    dim3 grid(n / ROWS_PER_WG);                    // 1024
    nltp_kernel<<<grid, NTHREADS, 0, stream>>>(x, W1, W2, tpw, out);
}